// Round 9
// baseline (245.440 us; speedup 1.0000x reference)
//
#include <hip/hip_runtime.h>
#include <cstdint>
#include <cstddef>

// ---------- types / helpers ----------
typedef __bf16 bf16x8 __attribute__((ext_vector_type(8)));
typedef float  f32x4  __attribute__((ext_vector_type(4)));
typedef unsigned short us;

#define DEV static __device__ __forceinline__

DEV us f2bf(float f) {
    unsigned int u = __builtin_bit_cast(unsigned int, f);
    u += 0x7FFFu + ((u >> 16) & 1u);   // RNE
    return (us)(u >> 16);
}
DEV unsigned int pack2bf(float a, float b) {   // [lo=a, hi=b], round-half-up (cheap)
    unsigned int ua = __builtin_bit_cast(unsigned int, a) + 0x8000u;
    unsigned int ub = __builtin_bit_cast(unsigned int, b) + 0x8000u;
    return (ua >> 16) | (ub & 0xFFFF0000u);    // -> v_perm_b32
}

DEV void gll16(const void* g, void* l) {   // 16B global->LDS direct (wave: +lane*16)
    __builtin_amdgcn_global_load_lds(
        (const __attribute__((address_space(1))) unsigned int*)g,
        (__attribute__((address_space(3))) unsigned int*)l, 16, 0, 0);
}

DEV bf16x8 ld_frag(const us* p) {
    return __builtin_bit_cast(bf16x8, *reinterpret_cast<const uint4*>(p));
}

// ---------- problem constants ----------
#define BB 4
#define TT 2048
#define CC 768
#define NH 12
#define DH 64
#define MM (BB*TT)          // 8192
#define QSCALE 0.1803368801111144f   // 0.125 * log2(e): softmax via exp2

// ---------- cast f32 -> bf16 ----------
__global__ __launch_bounds__(256)
void cast_k(const float* __restrict__ x, us* __restrict__ xb, int n4)
{
    int i = blockIdx.x * 256 + threadIdx.x;
    int stride = gridDim.x * 256;
    for (; i < n4; i += stride) {
        float4 f = reinterpret_cast<const float4*>(x)[i];
        ushort4 o;
        o.x = f2bf(f.x); o.y = f2bf(f.y); o.z = f2bf(f.z); o.w = f2bf(f.w);
        reinterpret_cast<ushort4*>(xb)[i] = o;
    }
}

// ---------- transpose f32 -> bf16: dst[Cc][R] = bf16(src[R][Cc]) ----------
__global__ __launch_bounds__(256)
void transpose_k(const float* __restrict__ src,
                 us* __restrict__ dst, int R, int Cc)
{
    __shared__ float tile[32][33];
    int c0 = blockIdx.x * 32, r0 = blockIdx.y * 32;
    int tx = threadIdx.x, ty = threadIdx.y;
#pragma unroll
    for (int i = 0; i < 4; ++i)
        tile[ty + i*8][tx] = src[(size_t)(r0 + ty + i*8) * Cc + c0 + tx];
    __syncthreads();
#pragma unroll
    for (int i = 0; i < 4; ++i)
        dst[(size_t)(c0 + ty + i*8) * R + r0 + tx] = f2bf(tile[tx][ty + i*8]);
}

// ---------- fraglet layouts (probe round 5: scattered frag loads = 81% of attn) ----------
// K packed so an attn K-frag wave-load is 1KB CONTIGUOUS:
//   offK(t,d) = (t>>4)*1024 + ((d>>3)&7)*128 + (t&15)*8 + (d&7)    [elems, per head]
//   frag (j,sub,hh): addr = (j*4+sub)*1024 + hh*512 + lane*8  (lane = quad*16+l16)
// V^T packed likewise:
//   offV(d,t) = (t>>6)*4096 + ((d>>4)&3)*1024 + ((t>>3)&7)*128 + (d&15)*8 + (t&7)
//   frag (j,dsub,kc): addr = j*4096 + dsub*1024 + kc*512 + lane*8
// Both bijective on [0, TT*DH).

// ---------- GEMM: C[M,N] = A[M,K](bf16) * Bt[N,K]^T + bias[N] ----------
// MODE 0: store f32 to Cout
// MODE 1: scatter qkv -> Qo(scaled)[B,H,T,D] / Ko fraglet / Vo fraglet  (bf16)
#define BM 128
#define BN 128
#define BK 32

template<int MODE>
__global__ __launch_bounds__(256)
void gemm_bt(const us* __restrict__ A,
             const us* __restrict__ Bt,
             const float* __restrict__ bias,
             float* __restrict__ Cout,
             us* __restrict__ Qo, us* __restrict__ Ko, us* __restrict__ Vo,
             int M, int N, int K)
{
    __shared__ __align__(16) us As[BM * BK];
    __shared__ __align__(16) us Bs[BN * BK];

    const int tid  = threadIdx.x;
    const int wave = tid >> 6, lane = tid & 63;
    const int quad = lane >> 4, l16 = lane & 15;
    const int waveM = (wave >> 1) * 64, waveN = (wave & 1) * 64;
    const int m0 = blockIdx.y * BM, n0 = blockIdx.x * BN;

    const f32x4 zero4 = {0.f, 0.f, 0.f, 0.f};
    f32x4 acc[4][4];
#pragma unroll
    for (int i = 0; i < 4; ++i)
#pragma unroll
        for (int j = 0; j < 4; ++j) acc[i][j] = zero4;

    const int lrow = lane >> 2, lch = (lane & 3) * 8;
    const int nk = K / BK;
    for (int kt = 0; kt < nk; ++kt) {
#pragma unroll
        for (int c = 0; c < 2; ++c) {
            int rb = (wave * 2 + c) * 16;
            int row = rb + lrow;
            gll16(A  + (size_t)(m0 + row) * K + kt * BK + lch, &As[rb * BK]);
            gll16(Bt + (size_t)(n0 + row) * K + kt * BK + lch, &Bs[rb * BK]);
        }
        __syncthreads();

        bf16x8 af[4], bfv[4];
#pragma unroll
        for (int mi = 0; mi < 4; ++mi)
            af[mi] = *reinterpret_cast<const bf16x8*>(&As[(waveM + mi * 16 + l16) * BK + quad * 8]);
#pragma unroll
        for (int ni = 0; ni < 4; ++ni)
            bfv[ni] = *reinterpret_cast<const bf16x8*>(&Bs[(waveN + ni * 16 + l16) * BK + quad * 8]);
#pragma unroll
        for (int mi = 0; mi < 4; ++mi)
#pragma unroll
            for (int ni = 0; ni < 4; ++ni)
                acc[mi][ni] = __builtin_amdgcn_mfma_f32_16x16x32_bf16(af[mi], bfv[ni], acc[mi][ni], 0, 0, 0);
        __syncthreads();
    }

    // epilogue: C/D layout col = l16, row = quad*4 + reg
#pragma unroll
    for (int mi = 0; mi < 4; ++mi) {
#pragma unroll
        for (int ni = 0; ni < 4; ++ni) {
            int n = n0 + waveN + ni * 16 + l16;
            float bv = bias[n];
            int mg = m0 + waveM + mi * 16 + quad * 4;   // first of 4 consecutive m
            if (MODE == 0) {
#pragma unroll
                for (int reg = 0; reg < 4; ++reg)
                    Cout[(size_t)(mg + reg) * N + n] = acc[mi][ni][reg] + bv;
            } else {
                int which = n / CC, c2 = n % CC;
                int h = c2 >> 6, d = c2 & 63;
                int b = mg >> 11, t0 = mg & 2047;
                size_t hb = (size_t)(b * NH + h) * TT * DH;
                if (which == 2) {
                    // V fraglet: 4 consecutive t stay contiguous -> one 8B store
                    size_t off = hb + (size_t)(t0 >> 6) * 4096 + (d >> 4) * 1024
                               + ((t0 >> 3) & 7) * 128 + (d & 15) * 8 + (t0 & 7);
                    ushort4 pk;
                    pk.x = f2bf(acc[mi][ni][0] + bv);
                    pk.y = f2bf(acc[mi][ni][1] + bv);
                    pk.z = f2bf(acc[mi][ni][2] + bv);
                    pk.w = f2bf(acc[mi][ni][3] + bv);
                    *reinterpret_cast<ushort4*>(Vo + off) = pk;
                } else if (which == 1) {
                    // K fraglet: per-reg scalar store, stride 8 elems
                    size_t off = hb + (size_t)(t0 >> 4) * 1024 + (d >> 3) * 128
                               + (t0 & 15) * 8 + (d & 7);
#pragma unroll
                    for (int reg = 0; reg < 4; ++reg)
                        Ko[off + reg * 8] = f2bf(acc[mi][ni][reg] + bv);
                } else {
#pragma unroll
                    for (int reg = 0; reg < 4; ++reg) {
                        size_t off = hb + (size_t)(t0 + reg) * DH + d;
                        Qo[off] = f2bf((acc[mi][ni][reg] + bv) * QSCALE);
                    }
                }
            }
        }
    }
}

// ---------- flash attention: fraglet + fixed-shift softmax + 2-deep reg prefetch ----------
// R7 structure (768 blocks x 2 waves, pair {pw,63-pw}, 33 tiles/wave, no barriers).
// R2/R3/R8 showed attn time invariant under wave redistribution at ~14% occupancy
// with all aggregate pipes <35% -> per-wave LATENCY chain is the binder: tile j's
// 16 frag loads were issued in the same iteration that consumes them (~4500 cyc
// stall/tile). Fix: double-buffer K/V frags in registers; each step issues tile
// j+1's loads FIRST (into the other named set - no runtime indexing), then
// computes tile j entirely from regs. Every compiler vmcnt then has 16 newer
// loads outstanding -> prefetch never drained; latency budget = full tile
// (~1000 cyc). VGPR +128 (4 frag sets), still under the 2-wave/SIMD cap.
#define PST 72

DEV void tile_step(const us* __restrict__ Kh, const us* __restrict__ Vh,
                   int jpref, int lane, int quad, int l16,
                   bf16x8 (&kf)[4][2], bf16x8 (&vf)[4][2],
                   bf16x8 (&kfN)[4][2], bf16x8 (&vfN)[4][2],
                   const bf16x8& qfA0, const bf16x8& qfA1,
                   const bf16x8& qfB0, const bf16x8& qfB1,
                   int domask, int keybase, int mA, int mB,
                   us* __restrict__ myP,
                   float& lrA, float& lrB, f32x4* oA, f32x4* oB)
{
    const f32x4 zero4 = {0.f, 0.f, 0.f, 0.f};

    // 1) prefetch next tile's K/V frags (before any wait on current frags)
    {
        const us* kbN = Kh + (size_t)jpref * 4096;
        const us* vbN = Vh + (size_t)jpref * 4096;
#pragma unroll
        for (int sub = 0; sub < 4; ++sub) {
            kfN[sub][0] = ld_frag(kbN + sub * 1024 +       lane * 8);
            kfN[sub][1] = ld_frag(kbN + sub * 1024 + 512 + lane * 8);
            vfN[sub][0] = ld_frag(vbN + sub * 1024 +       lane * 8);
            vfN[sub][1] = ld_frag(vbN + sub * 1024 + 512 + lane * 8);
        }
    }

    // 2) S^T = K Q^T (kf loaded a full tile ago)
    f32x4 sA[4], sB[4];
#pragma unroll
    for (int sub = 0; sub < 4; ++sub) {
        f32x4 t = __builtin_amdgcn_mfma_f32_16x16x32_bf16(kf[sub][0], qfA0, zero4, 0, 0, 0);
        sA[sub]  = __builtin_amdgcn_mfma_f32_16x16x32_bf16(kf[sub][1], qfA1, t, 0, 0, 0);
        f32x4 u = __builtin_amdgcn_mfma_f32_16x16x32_bf16(kf[sub][0], qfB0, zero4, 0, 0, 0);
        sB[sub]  = __builtin_amdgcn_mfma_f32_16x16x32_bf16(kf[sub][1], qfB1, u, 0, 0, 0);
    }

    // 3) diagonal mask (last tile of a masked range; exp2(-inf)=0)
    if (domask) {
#pragma unroll
        for (int sub = 0; sub < 4; ++sub)
#pragma unroll
            for (int reg = 0; reg < 4; ++reg) {
                int key = keybase + sub * 16 + quad * 4 + reg;
                if (key > mA) sA[sub][reg] = -INFINITY;
                if (key > mB) sB[sub][reg] = -INFINITY;
            }
    }

    // 4) fixed-shift softmax (no max tracking), group A
    {
        float rs = 0.f;
#pragma unroll
        for (int sub = 0; sub < 4; ++sub) {
            float p0 = exp2f(sA[sub][0]), p1 = exp2f(sA[sub][1]);
            float p2 = exp2f(sA[sub][2]), p3 = exp2f(sA[sub][3]);
            rs += (p0 + p1) + (p2 + p3);
            uint2 pk; pk.x = pack2bf(p0, p1); pk.y = pack2bf(p2, p3);
            *reinterpret_cast<uint2*>(&myP[l16 * PST + sub * 16 + quad * 4]) = pk;
        }
        rs += __shfl_xor(rs, 16);
        rs += __shfl_xor(rs, 32);
        lrA += rs;
    }
    // group B
    {
        float rs = 0.f;
#pragma unroll
        for (int sub = 0; sub < 4; ++sub) {
            float p0 = exp2f(sB[sub][0]), p1 = exp2f(sB[sub][1]);
            float p2 = exp2f(sB[sub][2]), p3 = exp2f(sB[sub][3]);
            rs += (p0 + p1) + (p2 + p3);
            uint2 pk; pk.x = pack2bf(p0, p1); pk.y = pack2bf(p2, p3);
            *reinterpret_cast<uint2*>(&myP[(16 + l16) * PST + sub * 16 + quad * 4]) = pk;
        }
        rs += __shfl_xor(rs, 16);
        rs += __shfl_xor(rs, 32);
        lrB += rs;
    }

    // 5) O^T += V^T P (vf loaded a full tile ago; P via same-wave LDS)
#pragma unroll
    for (int kc = 0; kc < 2; ++kc) {
        bf16x8 pfA = *reinterpret_cast<const bf16x8*>(&myP[l16 * PST + kc * 32 + quad * 8]);
        bf16x8 pfB = *reinterpret_cast<const bf16x8*>(&myP[(16 + l16) * PST + kc * 32 + quad * 8]);
#pragma unroll
        for (int d = 0; d < 4; ++d) {
            oA[d] = __builtin_amdgcn_mfma_f32_16x16x32_bf16(vf[d][kc], pfA, oA[d], 0, 0, 0);
            oB[d] = __builtin_amdgcn_mfma_f32_16x16x32_bf16(vf[d][kc], pfB, oB[d], 0, 0, 0);
        }
    }
}

__global__ __launch_bounds__(128)
void attn_k(const us* __restrict__ Qg,
            const us* __restrict__ Kg,   // fraglet layout
            const us* __restrict__ Vt,   // fraglet layout
            us* __restrict__ Og)
{
    __shared__ __align__(16) us Ps[2][32 * PST];   // per-wave P[g*16+m][key]

    const int tid  = threadIdx.x;
    const int wave = tid >> 6, lane = tid & 63;
    const int quad = lane >> 4, l16 = lane & 15;

    // XCD-locality decode: xcd = id%8 (round-robin dispatch heuristic)
    const int id  = blockIdx.x;
    const int xcd = id & 7, s = id >> 3;           // s in 0..95
    const int bh  = xcd + 8 * (s >> 4);            // head 0..47, fixed XCD
    const int q   = s & 15;                        // 0..15
    const int pw  = 2 * q + wave;                  // wave's pair index 0..31

    const us* Qh = Qg + (size_t)bh * TT * DH;
    const us* Kh = Kg + (size_t)bh * TT * DH;
    const us* Vh = Vt + (size_t)bh * TT * DH;
    const int b = bh / NH, h = bh % NH;
    us* myP = Ps[wave];

    const f32x4 zero4 = {0.f, 0.f, 0.f, 0.f};

#pragma unroll 1
    for (int seg = 0; seg < 2; ++seg) {
        const int g   = seg ? 63 - pw : pw;        // 32-row group index 0..63
        const int nkt = (g >> 1) + 1;              // key tiles of 64
        const int mA  = g * 32 + l16;              // group A query row
        const int mB  = mA + 16;                   // group B query row

        bf16x8 qfA0 = ld_frag(Qh + (size_t)mA * DH + quad * 8);
        bf16x8 qfA1 = ld_frag(Qh + (size_t)mA * DH + 32 + quad * 8);
        bf16x8 qfB0 = ld_frag(Qh + (size_t)mB * DH + quad * 8);
        bf16x8 qfB1 = ld_frag(Qh + (size_t)mB * DH + 32 + quad * 8);

        f32x4 oA[4], oB[4];
#pragma unroll
        for (int i = 0; i < 4; ++i) { oA[i] = zero4; oB[i] = zero4; }
        float lrA = 0.f, lrB = 0.f;

        // 2-deep register pipeline over key tiles
        bf16x8 kf0[4][2], vf0[4][2], kf1[4][2], vf1[4][2];
#pragma unroll
        for (int sub = 0; sub < 4; ++sub) {        // prologue: tile 0 -> set0
            kf0[sub][0] = ld_frag(Kh + sub * 1024 +       lane * 8);
            kf0[sub][1] = ld_frag(Kh + sub * 1024 + 512 + lane * 8);
            vf0[sub][0] = ld_frag(Vh + sub * 1024 +       lane * 8);
            vf0[sub][1] = ld_frag(Vh + sub * 1024 + 512 + lane * 8);
        }

        int j = 0;
#pragma unroll 1
        for (; j + 2 <= nkt; j += 2) {
            // even tile: compute set0, prefetch j+1 -> set1 (j+1 < nkt here)
            tile_step(Kh, Vh, j + 1, lane, quad, l16,
                      kf0, vf0, kf1, vf1, qfA0, qfA1, qfB0, qfB1,
                      0, j * 64, mA, mB, myP, lrA, lrB, oA, oB);
            // odd tile: compute set1, prefetch j+2 -> set0 (clamped; dead if last)
            int jn = (j + 2 < nkt) ? (j + 2) : 0;
            tile_step(Kh, Vh, jn, lane, quad, l16,
                      kf1, vf1, kf0, vf0, qfA0, qfA1, qfB0, qfB1,
                      (j + 2 == nkt) ? 1 : 0, (j + 1) * 64, mA, mB, myP, lrA, lrB, oA, oB);
        }
        if (j < nkt) {
            // tail odd tile (j == nkt-1), always masked; prefetch is dead
            tile_step(Kh, Vh, 0, lane, quad, l16,
                      kf0, vf0, kf1, vf1, qfA0, qfA1, qfB0, qfB1,
                      1, j * 64, mA, mB, myP, lrA, lrB, oA, oB);
        }

        // epilogue: O^T[d][m] -> att[b, t=m, h*64+d], 8B packed stores
        const float invA = 1.f / lrA, invB = 1.f / lrB;
        us* orowA = Og + ((size_t)(b * TT + mA)) * CC + h * DH;
        us* orowB = Og + ((size_t)(b * TT + mB)) * CC + h * DH;
#pragma unroll
        for (int d = 0; d < 4; ++d) {
            uint2 pa, pb;
            pa.x = pack2bf(oA[d][0] * invA, oA[d][1] * invA);
            pa.y = pack2bf(oA[d][2] * invA, oA[d][3] * invA);
            pb.x = pack2bf(oB[d][0] * invB, oB[d][1] * invB);
            pb.y = pack2bf(oB[d][2] * invB, oB[d][3] * invB);
            *reinterpret_cast<uint2*>(orowA + d * 16 + quad * 4) = pa;
            *reinterpret_cast<uint2*>(orowB + d * 16 + quad * 4) = pb;
        }
    }
}

// ---------- launch ----------
extern "C" void kernel_launch(void* const* d_in, const int* in_sizes, int n_in,
                              void* d_out, int out_size, void* d_ws, size_t ws_size,
                              hipStream_t stream)
{
    const float* x      = (const float*)d_in[0];
    const float* w_attn = (const float*)d_in[1];
    const float* b_attn = (const float*)d_in[2];
    const float* w_proj = (const float*)d_in[3];
    const float* b_proj = (const float*)d_in[4];
    float* out = (float*)d_out;

    char* ws = (char*)d_ws;
    size_t off = 0;
    auto alloc = [&](size_t bytes) {
        void* p = ws + off;
        off += (bytes + 255) & ~(size_t)255;
        return p;
    };
    us* wtA = (us*)alloc((size_t)(3 * CC) * CC * 2);  // [2304][768] bf16
    us* wtP = (us*)alloc((size_t)CC * CC * 2);        // [768][768]  bf16
    us* xb  = (us*)alloc((size_t)MM * CC * 2);        // x as bf16
    us* Qb  = (us*)alloc((size_t)MM * CC * 2);        // [B,H,T,D]
    us* Kb  = (us*)alloc((size_t)MM * CC * 2);        // K fraglet
    us* Vtb = (us*)alloc((size_t)MM * CC * 2);        // V fraglet
    us* att = (us*)alloc((size_t)MM * CC * 2);        // [B,T,C]

    cast_k<<<1024, 256, 0, stream>>>(x, xb, MM * CC / 4);
    transpose_k<<<dim3((3 * CC) / 32, CC / 32), dim3(32, 8), 0, stream>>>(w_attn, wtA, CC, 3 * CC);
    transpose_k<<<dim3(CC / 32, CC / 32), dim3(32, 8), 0, stream>>>(w_proj, wtP, CC, CC);

    gemm_bt<1><<<dim3((3 * CC) / BN, MM / BM), 256, 0, stream>>>(
        xb, wtA, b_attn, nullptr, Qb, Kb, Vtb, MM, 3 * CC, CC);

    attn_k<<<dim3(16 * BB * NH), 128, 0, stream>>>(Qb, Kb, Vtb, att);

    gemm_bt<0><<<dim3(CC / BN, MM / BM), 256, 0, stream>>>(
        att, wtP, b_proj, out, nullptr, nullptr, nullptr, MM, CC, CC);

    (void)in_sizes; (void)n_in; (void)out_size; (void)ws_size;
}

// Round 10
// 228.016 us; speedup vs baseline: 1.0764x; 1.0764x over previous
//
#include <hip/hip_runtime.h>
#include <cstdint>
#include <cstddef>

// ---------- types / helpers ----------
typedef __bf16 bf16x8 __attribute__((ext_vector_type(8)));
typedef float  f32x4  __attribute__((ext_vector_type(4)));
typedef unsigned short us;

#define DEV static __device__ __forceinline__

DEV us f2bf(float f) {
    unsigned int u = __builtin_bit_cast(unsigned int, f);
    u += 0x7FFFu + ((u >> 16) & 1u);   // RNE
    return (us)(u >> 16);
}
DEV unsigned int pack2bf(float a, float b) {   // [lo=a, hi=b], round-half-up (cheap)
    unsigned int ua = __builtin_bit_cast(unsigned int, a) + 0x8000u;
    unsigned int ub = __builtin_bit_cast(unsigned int, b) + 0x8000u;
    return (ua >> 16) | (ub & 0xFFFF0000u);    // -> v_perm_b32
}

DEV void gll16(const void* g, void* l) {   // 16B global->LDS direct (wave: +lane*16)
    __builtin_amdgcn_global_load_lds(
        (const __attribute__((address_space(1))) unsigned int*)g,
        (__attribute__((address_space(3))) unsigned int*)l, 16, 0, 0);
}

DEV bf16x8 ld_frag(const us* p) {
    return __builtin_bit_cast(bf16x8, *reinterpret_cast<const uint4*>(p));
}

// ---------- problem constants ----------
#define BB 4
#define TT 2048
#define CC 768
#define NH 12
#define DH 64
#define MM (BB*TT)          // 8192
#define QSCALE 0.1803368801111144f   // 0.125 * log2(e): softmax via exp2

// ---------- cast f32 -> bf16 ----------
__global__ __launch_bounds__(256)
void cast_k(const float* __restrict__ x, us* __restrict__ xb, int n4)
{
    int i = blockIdx.x * 256 + threadIdx.x;
    int stride = gridDim.x * 256;
    for (; i < n4; i += stride) {
        float4 f = reinterpret_cast<const float4*>(x)[i];
        ushort4 o;
        o.x = f2bf(f.x); o.y = f2bf(f.y); o.z = f2bf(f.z); o.w = f2bf(f.w);
        reinterpret_cast<ushort4*>(xb)[i] = o;
    }
}

// ---------- transpose f32 -> bf16: dst[Cc][R] = bf16(src[R][Cc]) ----------
__global__ __launch_bounds__(256)
void transpose_k(const float* __restrict__ src,
                 us* __restrict__ dst, int R, int Cc)
{
    __shared__ float tile[32][33];
    int c0 = blockIdx.x * 32, r0 = blockIdx.y * 32;
    int tx = threadIdx.x, ty = threadIdx.y;
#pragma unroll
    for (int i = 0; i < 4; ++i)
        tile[ty + i*8][tx] = src[(size_t)(r0 + ty + i*8) * Cc + c0 + tx];
    __syncthreads();
#pragma unroll
    for (int i = 0; i < 4; ++i)
        dst[(size_t)(c0 + ty + i*8) * R + r0 + tx] = f2bf(tile[tx][ty + i*8]);
}

// ---------- fraglet layouts (probe round 5: scattered frag loads = 81% of attn) ----------
// K packed so an attn K-frag wave-load is 1KB CONTIGUOUS:
//   offK(t,d) = (t>>4)*1024 + ((d>>3)&7)*128 + (t&15)*8 + (d&7)    [elems, per head]
//   frag (j,sub,hh): addr = (j*4+sub)*1024 + hh*512 + lane*8  (lane = quad*16+l16)
// V^T packed likewise:
//   offV(d,t) = (t>>6)*4096 + ((d>>4)&3)*1024 + ((t>>3)&7)*128 + (d&15)*8 + (t&7)
//   frag (j,dsub,kc): addr = j*4096 + dsub*1024 + kc*512 + lane*8
// Both bijective on [0, TT*DH).

// ---------- GEMM: C[M,N] = A[M,K](bf16) * Bt[N,K]^T + bias[N] ----------
// 2-phase double-buffered staging (catalog T3-minimum): issue next tile's
// global_load_lds into the OTHER LDS buffer BEFORE consuming the current one;
// ONE barrier per K-iter (its implicit vmcnt(0) drain publishes the staged buf).
// Was: stage -> barrier -> compute -> barrier (staging latency fully exposed).
// MODE 0: store f32 to Cout
// MODE 1: scatter qkv -> Qo(scaled)[B,H,T,D] / Ko fraglet / Vo fraglet  (bf16)
#define BM 128
#define BN 128
#define BK 32

template<int MODE>
__global__ __launch_bounds__(256)
void gemm_bt(const us* __restrict__ A,
             const us* __restrict__ Bt,
             const float* __restrict__ bias,
             float* __restrict__ Cout,
             us* __restrict__ Qo, us* __restrict__ Ko, us* __restrict__ Vo,
             int M, int N, int K)
{
    __shared__ __align__(16) us As[2][BM * BK];
    __shared__ __align__(16) us Bs[2][BN * BK];

    const int tid  = threadIdx.x;
    const int wave = tid >> 6, lane = tid & 63;
    const int quad = lane >> 4, l16 = lane & 15;
    const int waveM = (wave >> 1) * 64, waveN = (wave & 1) * 64;
    const int m0 = blockIdx.y * BM, n0 = blockIdx.x * BN;

    const f32x4 zero4 = {0.f, 0.f, 0.f, 0.f};
    f32x4 acc[4][4];
#pragma unroll
    for (int i = 0; i < 4; ++i)
#pragma unroll
        for (int j = 0; j < 4; ++j) acc[i][j] = zero4;

    const int lrow = lane >> 2, lch = (lane & 3) * 8;
    const int nk = K / BK;

    // stage K-tile kt into buffer buf
    auto STAGE = [&](int buf, int kt) {
#pragma unroll
        for (int c = 0; c < 2; ++c) {
            int rb = (wave * 2 + c) * 16;
            int row = rb + lrow;
            gll16(A  + (size_t)(m0 + row) * K + kt * BK + lch, &As[buf][rb * BK]);
            gll16(Bt + (size_t)(n0 + row) * K + kt * BK + lch, &Bs[buf][rb * BK]);
        }
    };

    STAGE(0, 0);
    __syncthreads();                    // vmcnt(0) drain: buf0 ready
    int cur = 0;

    for (int kt = 0; kt < nk; ++kt) {
        if (kt + 1 < nk) STAGE(cur ^ 1, kt + 1);   // prefetch into other buffer

        bf16x8 af[4], bfv[4];
#pragma unroll
        for (int mi = 0; mi < 4; ++mi)
            af[mi] = *reinterpret_cast<const bf16x8*>(&As[cur][(waveM + mi * 16 + l16) * BK + quad * 8]);
#pragma unroll
        for (int ni = 0; ni < 4; ++ni)
            bfv[ni] = *reinterpret_cast<const bf16x8*>(&Bs[cur][(waveN + ni * 16 + l16) * BK + quad * 8]);
#pragma unroll
        for (int mi = 0; mi < 4; ++mi)
#pragma unroll
            for (int ni = 0; ni < 4; ++ni)
                acc[mi][ni] = __builtin_amdgcn_mfma_f32_16x16x32_bf16(af[mi], bfv[ni], acc[mi][ni], 0, 0, 0);

        // one barrier/iter: all reads of buf[cur] done AND staging of buf[cur^1]
        // drained (compiler emits s_waitcnt vmcnt(0) lgkmcnt(0) before s_barrier)
        __syncthreads();
        cur ^= 1;
    }

    // epilogue: C/D layout col = l16, row = quad*4 + reg
#pragma unroll
    for (int mi = 0; mi < 4; ++mi) {
#pragma unroll
        for (int ni = 0; ni < 4; ++ni) {
            int n = n0 + waveN + ni * 16 + l16;
            float bv = bias[n];
            int mg = m0 + waveM + mi * 16 + quad * 4;   // first of 4 consecutive m
            if (MODE == 0) {
#pragma unroll
                for (int reg = 0; reg < 4; ++reg)
                    Cout[(size_t)(mg + reg) * N + n] = acc[mi][ni][reg] + bv;
            } else {
                int which = n / CC, c2 = n % CC;
                int h = c2 >> 6, d = c2 & 63;
                int b = mg >> 11, t0 = mg & 2047;
                size_t hb = (size_t)(b * NH + h) * TT * DH;
                if (which == 2) {
                    // V fraglet: 4 consecutive t stay contiguous -> one 8B store
                    size_t off = hb + (size_t)(t0 >> 6) * 4096 + (d >> 4) * 1024
                               + ((t0 >> 3) & 7) * 128 + (d & 15) * 8 + (t0 & 7);
                    ushort4 pk;
                    pk.x = f2bf(acc[mi][ni][0] + bv);
                    pk.y = f2bf(acc[mi][ni][1] + bv);
                    pk.z = f2bf(acc[mi][ni][2] + bv);
                    pk.w = f2bf(acc[mi][ni][3] + bv);
                    *reinterpret_cast<ushort4*>(Vo + off) = pk;
                } else if (which == 1) {
                    // K fraglet: per-reg scalar store, stride 8 elems
                    size_t off = hb + (size_t)(t0 >> 4) * 1024 + (d >> 3) * 128
                               + (t0 & 15) * 8 + (d & 7);
#pragma unroll
                    for (int reg = 0; reg < 4; ++reg)
                        Ko[off + reg * 8] = f2bf(acc[mi][ni][reg] + bv);
                } else {
#pragma unroll
                    for (int reg = 0; reg < 4; ++reg) {
                        size_t off = hb + (size_t)(t0 + reg) * DH + d;
                        Qo[off] = f2bf((acc[mi][ni][reg] + bv) * QSCALE);
                    }
                }
            }
        }
    }
}

// ---------- flash attention (round-7 verified: fraglet + fixed-shift softmax) ----------
// Grid 768 x 128 threads (2 waves), pair {pw, 63-pw}: 33 tiles/wave. No barriers.
// 75.4us verified; R8 (split-key) and R9 (reg prefetch) both regressed -> exact revert.
#define PST 72

__global__ __launch_bounds__(128)
void attn_k(const us* __restrict__ Qg,
            const us* __restrict__ Kg,   // fraglet layout
            const us* __restrict__ Vt,   // fraglet layout
            us* __restrict__ Og)
{
    __shared__ __align__(16) us Ps[2][32 * PST];   // per-wave P[g*16+m][key]

    const int tid  = threadIdx.x;
    const int wave = tid >> 6, lane = tid & 63;
    const int quad = lane >> 4, l16 = lane & 15;

    // XCD-locality decode: xcd = id%8 (round-robin dispatch heuristic)
    const int id  = blockIdx.x;
    const int xcd = id & 7, s = id >> 3;           // s in 0..95
    const int bh  = xcd + 8 * (s >> 4);            // head 0..47, fixed XCD
    const int q   = s & 15;                        // 0..15
    const int pw  = 2 * q + wave;                  // wave's pair index 0..31

    const size_t base = (size_t)bh * TT * DH;      // Q/K/V all TT*DH per head
    const int b = bh / NH, h = bh % NH;
    us* myP = Ps[wave];

    const f32x4 zero4 = {0.f, 0.f, 0.f, 0.f};

#pragma unroll 1
    for (int seg = 0; seg < 2; ++seg) {
        const int g   = seg ? 63 - pw : pw;        // 32-row group index 0..63
        const int nkt = (g >> 1) + 1;              // key tiles of 64
        const int mA  = g * 32 + l16;              // group A query row
        const int mB  = mA + 16;                   // group B query row

        bf16x8 qfA0 = ld_frag(Qg + base + (size_t)mA * DH + quad * 8);
        bf16x8 qfA1 = ld_frag(Qg + base + (size_t)mA * DH + 32 + quad * 8);
        bf16x8 qfB0 = ld_frag(Qg + base + (size_t)mB * DH + quad * 8);
        bf16x8 qfB1 = ld_frag(Qg + base + (size_t)mB * DH + 32 + quad * 8);

        f32x4 oA[4], oB[4];
#pragma unroll
        for (int i = 0; i < 4; ++i) { oA[i] = zero4; oB[i] = zero4; }
        float lrA = 0.f, lrB = 0.f;                // running denominators only

#pragma unroll 1
        for (int j = 0; j < nkt; ++j) {
            const us* kb = Kg + base + (size_t)j * 4096;   // fraglet tile
            const us* vb = Vt + base + (size_t)j * 4096;

            // K frags: frag (sub,hh) = 1KB contiguous wave-load
            bf16x8 kf[4][2];
#pragma unroll
            for (int sub = 0; sub < 4; ++sub)
#pragma unroll
                for (int hh = 0; hh < 2; ++hh)
                    kf[sub][hh] = ld_frag(kb + sub * 1024 + hh * 512 + lane * 8);

            // S^T = K Q^T for both groups (K frags shared)
            f32x4 sA[4], sB[4];
#pragma unroll
            for (int sub = 0; sub < 4; ++sub) {
                f32x4 t = __builtin_amdgcn_mfma_f32_16x16x32_bf16(kf[sub][0], qfA0, zero4, 0, 0, 0);
                sA[sub]  = __builtin_amdgcn_mfma_f32_16x16x32_bf16(kf[sub][1], qfA1, t, 0, 0, 0);
                f32x4 u = __builtin_amdgcn_mfma_f32_16x16x32_bf16(kf[sub][0], qfB0, zero4, 0, 0, 0);
                sB[sub]  = __builtin_amdgcn_mfma_f32_16x16x32_bf16(kf[sub][1], qfB1, u, 0, 0, 0);
            }

            // V frags: frag (dsub,kc) = 1KB contiguous wave-load
            bf16x8 vf[4][2];
#pragma unroll
            for (int dsub = 0; dsub < 4; ++dsub)
#pragma unroll
                for (int kc = 0; kc < 2; ++kc)
                    vf[dsub][kc] = ld_frag(vb + dsub * 1024 + kc * 512 + lane * 8);

            // diagonal mask on last tile (exp2(-inf) = 0)
            if (j == nkt - 1) {
#pragma unroll
                for (int sub = 0; sub < 4; ++sub)
#pragma unroll
                    for (int reg = 0; reg < 4; ++reg) {
                        int key = j * 64 + sub * 16 + quad * 4 + reg;
                        if (key > mA) sA[sub][reg] = -INFINITY;
                        if (key > mB) sB[sub][reg] = -INFINITY;
                    }
            }

            // fixed-shift softmax, group A: p = exp2(s), no max tracking
            {
                float rs = 0.f;
#pragma unroll
                for (int sub = 0; sub < 4; ++sub) {
                    float p0 = exp2f(sA[sub][0]), p1 = exp2f(sA[sub][1]);
                    float p2 = exp2f(sA[sub][2]), p3 = exp2f(sA[sub][3]);
                    rs += (p0 + p1) + (p2 + p3);
                    uint2 pk; pk.x = pack2bf(p0, p1); pk.y = pack2bf(p2, p3);
                    *reinterpret_cast<uint2*>(&myP[l16 * PST + sub * 16 + quad * 4]) = pk;
                }
                rs += __shfl_xor(rs, 16);
                rs += __shfl_xor(rs, 32);
                lrA += rs;
            }
            // group B
            {
                float rs = 0.f;
#pragma unroll
                for (int sub = 0; sub < 4; ++sub) {
                    float p0 = exp2f(sB[sub][0]), p1 = exp2f(sB[sub][1]);
                    float p2 = exp2f(sB[sub][2]), p3 = exp2f(sB[sub][3]);
                    rs += (p0 + p1) + (p2 + p3);
                    uint2 pk; pk.x = pack2bf(p0, p1); pk.y = pack2bf(p2, p3);
                    *reinterpret_cast<uint2*>(&myP[(16 + l16) * PST + sub * 16 + quad * 4]) = pk;
                }
                rs += __shfl_xor(rs, 16);
                rs += __shfl_xor(rs, 32);
                lrB += rs;
            }

            // O^T += V^T P (V frags shared A/B; same-wave LDS dep -> compiler waits)
#pragma unroll
            for (int kc = 0; kc < 2; ++kc) {
                bf16x8 pfA = *reinterpret_cast<const bf16x8*>(&myP[l16 * PST + kc * 32 + quad * 8]);
                bf16x8 pfB = *reinterpret_cast<const bf16x8*>(&myP[(16 + l16) * PST + kc * 32 + quad * 8]);
#pragma unroll
                for (int d = 0; d < 4; ++d) {
                    oA[d] = __builtin_amdgcn_mfma_f32_16x16x32_bf16(vf[d][kc], pfA, oA[d], 0, 0, 0);
                    oB[d] = __builtin_amdgcn_mfma_f32_16x16x32_bf16(vf[d][kc], pfB, oB[d], 0, 0, 0);
                }
            }
        }

        // epilogue: O^T[d][m] -> att[b, t=m, h*64+d], 8B packed stores
        const float invA = 1.f / lrA, invB = 1.f / lrB;
        us* orowA = Og + ((size_t)(b * TT + mA)) * CC + h * DH;
        us* orowB = Og + ((size_t)(b * TT + mB)) * CC + h * DH;
#pragma unroll
        for (int d = 0; d < 4; ++d) {
            uint2 pa, pb;
            pa.x = pack2bf(oA[d][0] * invA, oA[d][1] * invA);
            pa.y = pack2bf(oA[d][2] * invA, oA[d][3] * invA);
            pb.x = pack2bf(oB[d][0] * invB, oB[d][1] * invB);
            pb.y = pack2bf(oB[d][2] * invB, oB[d][3] * invB);
            *reinterpret_cast<uint2*>(orowA + d * 16 + quad * 4) = pa;
            *reinterpret_cast<uint2*>(orowB + d * 16 + quad * 4) = pb;
        }
    }
}

// ---------- launch ----------
extern "C" void kernel_launch(void* const* d_in, const int* in_sizes, int n_in,
                              void* d_out, int out_size, void* d_ws, size_t ws_size,
                              hipStream_t stream)
{
    const float* x      = (const float*)d_in[0];
    const float* w_attn = (const float*)d_in[1];
    const float* b_attn = (const float*)d_in[2];
    const float* w_proj = (const float*)d_in[3];
    const float* b_proj = (const float*)d_in[4];
    float* out = (float*)d_out;

    char* ws = (char*)d_ws;
    size_t off = 0;
    auto alloc = [&](size_t bytes) {
        void* p = ws + off;
        off += (bytes + 255) & ~(size_t)255;
        return p;
    };
    us* wtA = (us*)alloc((size_t)(3 * CC) * CC * 2);  // [2304][768] bf16
    us* wtP = (us*)alloc((size_t)CC * CC * 2);        // [768][768]  bf16
    us* xb  = (us*)alloc((size_t)MM * CC * 2);        // x as bf16
    us* Qb  = (us*)alloc((size_t)MM * CC * 2);        // [B,H,T,D]
    us* Kb  = (us*)alloc((size_t)MM * CC * 2);        // K fraglet
    us* Vtb = (us*)alloc((size_t)MM * CC * 2);        // V fraglet
    us* att = (us*)alloc((size_t)MM * CC * 2);        // [B,T,C]

    cast_k<<<1024, 256, 0, stream>>>(x, xb, MM * CC / 4);
    transpose_k<<<dim3((3 * CC) / 32, CC / 32), dim3(32, 8), 0, stream>>>(w_attn, wtA, CC, 3 * CC);
    transpose_k<<<dim3(CC / 32, CC / 32), dim3(32, 8), 0, stream>>>(w_proj, wtP, CC, CC);

    gemm_bt<1><<<dim3((3 * CC) / BN, MM / BM), 256, 0, stream>>>(
        xb, wtA, b_attn, nullptr, Qb, Kb, Vtb, MM, 3 * CC, CC);

    attn_k<<<dim3(16 * BB * NH), 128, 0, stream>>>(Qb, Kb, Vtb, att);

    gemm_bt<0><<<dim3(CC / BN, MM / BM), 256, 0, stream>>>(
        att, wtP, b_proj, out, nullptr, nullptr, nullptr, MM, CC, CC);

    (void)in_sizes; (void)n_in; (void)out_size; (void)ws_size;
}

// Round 11
// 222.600 us; speedup vs baseline: 1.1026x; 1.0243x over previous
//
#include <hip/hip_runtime.h>
#include <cstdint>
#include <cstddef>

// ---------- types / helpers ----------
typedef __bf16 bf16x8 __attribute__((ext_vector_type(8)));
typedef float  f32x4  __attribute__((ext_vector_type(4)));
typedef unsigned short us;

#define DEV static __device__ __forceinline__

DEV us f2bf(float f) {
    unsigned int u = __builtin_bit_cast(unsigned int, f);
    u += 0x7FFFu + ((u >> 16) & 1u);   // RNE
    return (us)(u >> 16);
}
DEV unsigned int pack2bf(float a, float b) {   // [lo=a, hi=b], round-half-up (cheap)
    unsigned int ua = __builtin_bit_cast(unsigned int, a) + 0x8000u;
    unsigned int ub = __builtin_bit_cast(unsigned int, b) + 0x8000u;
    return (ua >> 16) | (ub & 0xFFFF0000u);    // -> v_perm_b32
}

DEV void gll16(const void* g, void* l) {   // 16B global->LDS direct (wave: +lane*16)
    __builtin_amdgcn_global_load_lds(
        (const __attribute__((address_space(1))) unsigned int*)g,
        (__attribute__((address_space(3))) unsigned int*)l, 16, 0, 0);
}

DEV bf16x8 ld_frag(const us* p) {
    return __builtin_bit_cast(bf16x8, *reinterpret_cast<const uint4*>(p));
}

// ---------- problem constants ----------
#define BB 4
#define TT 2048
#define CC 768
#define NH 12
#define DH 64
#define MM (BB*TT)          // 8192
#define QSCALE 0.1803368801111144f   // 0.125 * log2(e): softmax via exp2

// ---------- fused prep: cast x->bf16 | transpose w_attn | transpose w_proj ----------
// One dispatch instead of three (6 serial launches -> 4 total in the pipeline).
// Block ranges: [0,1024) cast grid-stride; [1024,2752) w_attn 32x32 transpose
// tiles; [2752,3328) w_proj tiles. Per-op code identical to the old kernels.
#define PREP_CAST_BLK 1024
#define PREP_TA_BLK   ((3*CC/32)*(CC/32))   // 72*24 = 1728
#define PREP_TP_BLK   ((CC/32)*(CC/32))     // 24*24 = 576

__global__ __launch_bounds__(256)
void prep_k(const float* __restrict__ x, us* __restrict__ xb,
            const float* __restrict__ wA, us* __restrict__ wAt,
            const float* __restrict__ wP, us* __restrict__ wPt)
{
    const int bid = blockIdx.x;
    const int tid = threadIdx.x;

    if (bid < PREP_CAST_BLK) {
        const int n4 = MM * CC / 4;
        int i = bid * 256 + tid;
        const int stride = PREP_CAST_BLK * 256;
        for (; i < n4; i += stride) {
            float4 f = reinterpret_cast<const float4*>(x)[i];
            ushort4 o;
            o.x = f2bf(f.x); o.y = f2bf(f.y); o.z = f2bf(f.z); o.w = f2bf(f.w);
            reinterpret_cast<ushort4*>(xb)[i] = o;
        }
        return;
    }

    // transpose path: dst[Cc][R] = bf16(src[R][Cc]), 32x32 tiles, threads (32,8)
    __shared__ float tile[32][33];
    const float* src; us* dst; int R, Cc, tb;
    if (bid < PREP_CAST_BLK + PREP_TA_BLK) {
        src = wA; dst = wAt; R = CC; Cc = 3 * CC; tb = bid - PREP_CAST_BLK;
    } else {
        src = wP; dst = wPt; R = CC; Cc = CC;     tb = bid - PREP_CAST_BLK - PREP_TA_BLK;
    }
    const int gx = Cc / 32;
    const int c0 = (tb % gx) * 32, r0 = (tb / gx) * 32;
    const int tx = tid & 31, ty = tid >> 5;
#pragma unroll
    for (int i = 0; i < 4; ++i)
        tile[ty + i*8][tx] = src[(size_t)(r0 + ty + i*8) * Cc + c0 + tx];
    __syncthreads();
#pragma unroll
    for (int i = 0; i < 4; ++i)
        dst[(size_t)(c0 + ty + i*8) * R + r0 + tx] = f2bf(tile[tx][ty + i*8]);
}

// ---------- fraglet layouts (probe round 5: scattered frag loads = 81% of attn) ----------
// K packed so an attn K-frag wave-load is 1KB CONTIGUOUS:
//   offK(t,d) = (t>>4)*1024 + ((d>>3)&7)*128 + (t&15)*8 + (d&7)    [elems, per head]
//   frag (j,sub,hh): addr = (j*4+sub)*1024 + hh*512 + lane*8  (lane = quad*16+l16)
// V^T packed likewise:
//   offV(d,t) = (t>>6)*4096 + ((d>>4)&3)*1024 + ((t>>3)&7)*128 + (d&15)*8 + (t&7)
//   frag (j,dsub,kc): addr = j*4096 + dsub*1024 + kc*512 + lane*8
// Both bijective on [0, TT*DH).

// ---------- GEMM: C[M,N] = A[M,K](bf16) * Bt[N,K]^T + bias[N] ----------
// 2-phase double-buffered staging: issue next tile's global_load_lds into the
// OTHER LDS buffer BEFORE consuming the current one; ONE barrier per K-iter.
// MODE 0: store f32 to Cout
// MODE 1: scatter qkv -> Qo(scaled)[B,H,T,D] / Ko fraglet / Vo fraglet  (bf16)
#define BM 128
#define BN 128
#define BK 32

template<int MODE>
__global__ __launch_bounds__(256)
void gemm_bt(const us* __restrict__ A,
             const us* __restrict__ Bt,
             const float* __restrict__ bias,
             float* __restrict__ Cout,
             us* __restrict__ Qo, us* __restrict__ Ko, us* __restrict__ Vo,
             int M, int N, int K)
{
    __shared__ __align__(16) us As[2][BM * BK];
    __shared__ __align__(16) us Bs[2][BN * BK];

    const int tid  = threadIdx.x;
    const int wave = tid >> 6, lane = tid & 63;
    const int quad = lane >> 4, l16 = lane & 15;
    const int waveM = (wave >> 1) * 64, waveN = (wave & 1) * 64;
    const int m0 = blockIdx.y * BM, n0 = blockIdx.x * BN;

    const f32x4 zero4 = {0.f, 0.f, 0.f, 0.f};
    f32x4 acc[4][4];
#pragma unroll
    for (int i = 0; i < 4; ++i)
#pragma unroll
        for (int j = 0; j < 4; ++j) acc[i][j] = zero4;

    const int lrow = lane >> 2, lch = (lane & 3) * 8;
    const int nk = K / BK;

    auto STAGE = [&](int buf, int kt) {
#pragma unroll
        for (int c = 0; c < 2; ++c) {
            int rb = (wave * 2 + c) * 16;
            int row = rb + lrow;
            gll16(A  + (size_t)(m0 + row) * K + kt * BK + lch, &As[buf][rb * BK]);
            gll16(Bt + (size_t)(n0 + row) * K + kt * BK + lch, &Bs[buf][rb * BK]);
        }
    };

    STAGE(0, 0);
    __syncthreads();                    // vmcnt(0) drain: buf0 ready
    int cur = 0;

    for (int kt = 0; kt < nk; ++kt) {
        if (kt + 1 < nk) STAGE(cur ^ 1, kt + 1);   // prefetch into other buffer

        bf16x8 af[4], bfv[4];
#pragma unroll
        for (int mi = 0; mi < 4; ++mi)
            af[mi] = *reinterpret_cast<const bf16x8*>(&As[cur][(waveM + mi * 16 + l16) * BK + quad * 8]);
#pragma unroll
        for (int ni = 0; ni < 4; ++ni)
            bfv[ni] = *reinterpret_cast<const bf16x8*>(&Bs[cur][(waveN + ni * 16 + l16) * BK + quad * 8]);
#pragma unroll
        for (int mi = 0; mi < 4; ++mi)
#pragma unroll
            for (int ni = 0; ni < 4; ++ni)
                acc[mi][ni] = __builtin_amdgcn_mfma_f32_16x16x32_bf16(af[mi], bfv[ni], acc[mi][ni], 0, 0, 0);

        __syncthreads();
        cur ^= 1;
    }

    // epilogue: C/D layout col = l16, row = quad*4 + reg
#pragma unroll
    for (int mi = 0; mi < 4; ++mi) {
#pragma unroll
        for (int ni = 0; ni < 4; ++ni) {
            int n = n0 + waveN + ni * 16 + l16;
            float bv = bias[n];
            int mg = m0 + waveM + mi * 16 + quad * 4;   // first of 4 consecutive m
            if (MODE == 0) {
#pragma unroll
                for (int reg = 0; reg < 4; ++reg)
                    Cout[(size_t)(mg + reg) * N + n] = acc[mi][ni][reg] + bv;
            } else {
                int which = n / CC, c2 = n % CC;
                int h = c2 >> 6, d = c2 & 63;
                int b = mg >> 11, t0 = mg & 2047;
                size_t hb = (size_t)(b * NH + h) * TT * DH;
                if (which == 2) {
                    // V fraglet: 4 consecutive t stay contiguous -> one 8B store
                    size_t off = hb + (size_t)(t0 >> 6) * 4096 + (d >> 4) * 1024
                               + ((t0 >> 3) & 7) * 128 + (d & 15) * 8 + (t0 & 7);
                    ushort4 pk;
                    pk.x = f2bf(acc[mi][ni][0] + bv);
                    pk.y = f2bf(acc[mi][ni][1] + bv);
                    pk.z = f2bf(acc[mi][ni][2] + bv);
                    pk.w = f2bf(acc[mi][ni][3] + bv);
                    *reinterpret_cast<ushort4*>(Vo + off) = pk;
                } else if (which == 1) {
                    // K fraglet: per-reg scalar store, stride 8 elems
                    size_t off = hb + (size_t)(t0 >> 4) * 1024 + (d >> 3) * 128
                               + (t0 & 15) * 8 + (d & 7);
#pragma unroll
                    for (int reg = 0; reg < 4; ++reg)
                        Ko[off + reg * 8] = f2bf(acc[mi][ni][reg] + bv);
                } else {
#pragma unroll
                    for (int reg = 0; reg < 4; ++reg) {
                        size_t off = hb + (size_t)(t0 + reg) * DH + d;
                        Qo[off] = f2bf((acc[mi][ni][reg] + bv) * QSCALE);
                    }
                }
            }
        }
    }
}

// ---------- flash attention: fraglet + fixed-shift softmax + deferred l-reduce ----------
// R7 verified structure (768 blocks x 2 waves, pair {pw,63-pw}, 33 tiles/wave,
// no barriers). New: the per-tile cross-quad shfl_xor chains for the softmax
// denominator are DEFERRED - each lane keeps a per-lane partial sum (its own
// quad's keys) across all tiles; one shfl_xor(16)+shfl_xor(32) after the loop.
// Removes ~130 serial cross-lane ops per wave from the tile loop.
#define PST 72

__global__ __launch_bounds__(128)
void attn_k(const us* __restrict__ Qg,
            const us* __restrict__ Kg,   // fraglet layout
            const us* __restrict__ Vt,   // fraglet layout
            us* __restrict__ Og)
{
    __shared__ __align__(16) us Ps[2][32 * PST];   // per-wave P[g*16+m][key]

    const int tid  = threadIdx.x;
    const int wave = tid >> 6, lane = tid & 63;
    const int quad = lane >> 4, l16 = lane & 15;

    // XCD-locality decode: xcd = id%8 (round-robin dispatch heuristic)
    const int id  = blockIdx.x;
    const int xcd = id & 7, s = id >> 3;           // s in 0..95
    const int bh  = xcd + 8 * (s >> 4);            // head 0..47, fixed XCD
    const int q   = s & 15;                        // 0..15
    const int pw  = 2 * q + wave;                  // wave's pair index 0..31

    const size_t base = (size_t)bh * TT * DH;      // Q/K/V all TT*DH per head
    const int b = bh / NH, h = bh % NH;
    us* myP = Ps[wave];

    const f32x4 zero4 = {0.f, 0.f, 0.f, 0.f};

#pragma unroll 1
    for (int seg = 0; seg < 2; ++seg) {
        const int g   = seg ? 63 - pw : pw;        // 32-row group index 0..63
        const int nkt = (g >> 1) + 1;              // key tiles of 64
        const int mA  = g * 32 + l16;              // group A query row
        const int mB  = mA + 16;                   // group B query row

        bf16x8 qfA0 = ld_frag(Qg + base + (size_t)mA * DH + quad * 8);
        bf16x8 qfA1 = ld_frag(Qg + base + (size_t)mA * DH + 32 + quad * 8);
        bf16x8 qfB0 = ld_frag(Qg + base + (size_t)mB * DH + quad * 8);
        bf16x8 qfB1 = ld_frag(Qg + base + (size_t)mB * DH + 32 + quad * 8);

        f32x4 oA[4], oB[4];
#pragma unroll
        for (int i = 0; i < 4; ++i) { oA[i] = zero4; oB[i] = zero4; }
        float lrA = 0.f, lrB = 0.f;   // PER-LANE partial denominators (this quad's keys)

#pragma unroll 1
        for (int j = 0; j < nkt; ++j) {
            const us* kb = Kg + base + (size_t)j * 4096;   // fraglet tile
            const us* vb = Vt + base + (size_t)j * 4096;

            // K frags: frag (sub,hh) = 1KB contiguous wave-load
            bf16x8 kf[4][2];
#pragma unroll
            for (int sub = 0; sub < 4; ++sub)
#pragma unroll
                for (int hh = 0; hh < 2; ++hh)
                    kf[sub][hh] = ld_frag(kb + sub * 1024 + hh * 512 + lane * 8);

            // S^T = K Q^T for both groups (K frags shared)
            f32x4 sA[4], sB[4];
#pragma unroll
            for (int sub = 0; sub < 4; ++sub) {
                f32x4 t = __builtin_amdgcn_mfma_f32_16x16x32_bf16(kf[sub][0], qfA0, zero4, 0, 0, 0);
                sA[sub]  = __builtin_amdgcn_mfma_f32_16x16x32_bf16(kf[sub][1], qfA1, t, 0, 0, 0);
                f32x4 u = __builtin_amdgcn_mfma_f32_16x16x32_bf16(kf[sub][0], qfB0, zero4, 0, 0, 0);
                sB[sub]  = __builtin_amdgcn_mfma_f32_16x16x32_bf16(kf[sub][1], qfB1, u, 0, 0, 0);
            }

            // V frags: frag (dsub,kc) = 1KB contiguous wave-load
            bf16x8 vf[4][2];
#pragma unroll
            for (int dsub = 0; dsub < 4; ++dsub)
#pragma unroll
                for (int kc = 0; kc < 2; ++kc)
                    vf[dsub][kc] = ld_frag(vb + dsub * 1024 + kc * 512 + lane * 8);

            // diagonal mask on last tile (exp2(-inf) = 0)
            if (j == nkt - 1) {
#pragma unroll
                for (int sub = 0; sub < 4; ++sub)
#pragma unroll
                    for (int reg = 0; reg < 4; ++reg) {
                        int key = j * 64 + sub * 16 + quad * 4 + reg;
                        if (key > mA) sA[sub][reg] = -INFINITY;
                        if (key > mB) sB[sub][reg] = -INFINITY;
                    }
            }

            // fixed-shift softmax, group A: p = exp2(s); per-lane partial sum only
            {
                float rs = 0.f;
#pragma unroll
                for (int sub = 0; sub < 4; ++sub) {
                    float p0 = exp2f(sA[sub][0]), p1 = exp2f(sA[sub][1]);
                    float p2 = exp2f(sA[sub][2]), p3 = exp2f(sA[sub][3]);
                    rs += (p0 + p1) + (p2 + p3);
                    uint2 pk; pk.x = pack2bf(p0, p1); pk.y = pack2bf(p2, p3);
                    *reinterpret_cast<uint2*>(&myP[l16 * PST + sub * 16 + quad * 4]) = pk;
                }
                lrA += rs;
            }
            // group B
            {
                float rs = 0.f;
#pragma unroll
                for (int sub = 0; sub < 4; ++sub) {
                    float p0 = exp2f(sB[sub][0]), p1 = exp2f(sB[sub][1]);
                    float p2 = exp2f(sB[sub][2]), p3 = exp2f(sB[sub][3]);
                    rs += (p0 + p1) + (p2 + p3);
                    uint2 pk; pk.x = pack2bf(p0, p1); pk.y = pack2bf(p2, p3);
                    *reinterpret_cast<uint2*>(&myP[(16 + l16) * PST + sub * 16 + quad * 4]) = pk;
                }
                lrB += rs;
            }

            // O^T += V^T P (V frags shared A/B; same-wave LDS dep -> compiler waits)
#pragma unroll
            for (int kc = 0; kc < 2; ++kc) {
                bf16x8 pfA = *reinterpret_cast<const bf16x8*>(&myP[l16 * PST + kc * 32 + quad * 8]);
                bf16x8 pfB = *reinterpret_cast<const bf16x8*>(&myP[(16 + l16) * PST + kc * 32 + quad * 8]);
#pragma unroll
                for (int d = 0; d < 4; ++d) {
                    oA[d] = __builtin_amdgcn_mfma_f32_16x16x32_bf16(vf[d][kc], pfA, oA[d], 0, 0, 0);
                    oB[d] = __builtin_amdgcn_mfma_f32_16x16x32_bf16(vf[d][kc], pfB, oB[d], 0, 0, 0);
                }
            }
        }

        // deferred cross-quad denominator reduce (row = l16, partials across quads)
        lrA += __shfl_xor(lrA, 16); lrA += __shfl_xor(lrA, 32);
        lrB += __shfl_xor(lrB, 16); lrB += __shfl_xor(lrB, 32);

        // epilogue: O^T[d][m] -> att[b, t=m, h*64+d], 8B packed stores
        const float invA = 1.f / lrA, invB = 1.f / lrB;
        us* orowA = Og + ((size_t)(b * TT + mA)) * CC + h * DH;
        us* orowB = Og + ((size_t)(b * TT + mB)) * CC + h * DH;
#pragma unroll
        for (int d = 0; d < 4; ++d) {
            uint2 pa, pb;
            pa.x = pack2bf(oA[d][0] * invA, oA[d][1] * invA);
            pa.y = pack2bf(oA[d][2] * invA, oA[d][3] * invA);
            pb.x = pack2bf(oB[d][0] * invB, oB[d][1] * invB);
            pb.y = pack2bf(oB[d][2] * invB, oB[d][3] * invB);
            *reinterpret_cast<uint2*>(orowA + d * 16 + quad * 4) = pa;
            *reinterpret_cast<uint2*>(orowB + d * 16 + quad * 4) = pb;
        }
    }
}

// ---------- launch ----------
extern "C" void kernel_launch(void* const* d_in, const int* in_sizes, int n_in,
                              void* d_out, int out_size, void* d_ws, size_t ws_size,
                              hipStream_t stream)
{
    const float* x      = (const float*)d_in[0];
    const float* w_attn = (const float*)d_in[1];
    const float* b_attn = (const float*)d_in[2];
    const float* w_proj = (const float*)d_in[3];
    const float* b_proj = (const float*)d_in[4];
    float* out = (float*)d_out;

    char* ws = (char*)d_ws;
    size_t off = 0;
    auto alloc = [&](size_t bytes) {
        void* p = ws + off;
        off += (bytes + 255) & ~(size_t)255;
        return p;
    };
    us* wtA = (us*)alloc((size_t)(3 * CC) * CC * 2);  // [2304][768] bf16
    us* wtP = (us*)alloc((size_t)CC * CC * 2);        // [768][768]  bf16
    us* xb  = (us*)alloc((size_t)MM * CC * 2);        // x as bf16
    us* Qb  = (us*)alloc((size_t)MM * CC * 2);        // [B,H,T,D]
    us* Kb  = (us*)alloc((size_t)MM * CC * 2);        // K fraglet
    us* Vtb = (us*)alloc((size_t)MM * CC * 2);        // V fraglet
    us* att = (us*)alloc((size_t)MM * CC * 2);        // [B,T,C]

    prep_k<<<PREP_CAST_BLK + PREP_TA_BLK + PREP_TP_BLK, 256, 0, stream>>>(
        x, xb, w_attn, wtA, w_proj, wtP);

    gemm_bt<1><<<dim3((3 * CC) / BN, MM / BM), 256, 0, stream>>>(
        xb, wtA, b_attn, nullptr, Qb, Kb, Vtb, MM, 3 * CC, CC);

    attn_k<<<dim3(16 * BB * NH), 128, 0, stream>>>(Qb, Kb, Vtb, att);

    gemm_bt<0><<<dim3(CC / BN, MM / BM), 256, 0, stream>>>(
        att, wtP, b_proj, out, nullptr, nullptr, nullptr, MM, CC, CC);

    (void)in_sizes; (void)n_in; (void)out_size; (void)ws_size;
}